// Round 1
// baseline (630.426 us; speedup 1.0000x reference)
//
#include <hip/hip_runtime.h>
#include <math.h>

// Problem constants (fixed by setup_inputs)
#define B_ 4
#define C_ 64
#define N_ 16384
#define K_ 16
#define H_ 8
#define CP 67            // C + 3 (xyz concat)
#define CPAD 68          // padded to 17 float4
#define NP 16            // points per block
#define QSTRIDE 65       // q_lds row stride (bank spread)
#define ESTRIDE 552      // e_lds row stride: 8*68 + 8 -> p-groups 8 banks apart

// Padded / pre-scaled weights (rewritten every launch by setup_weights)
__device__ __align__(16) float wpad[3 * C_ * CPAD];

__global__ void setup_weights(const float* __restrict__ Wq,
                              const float* __restrict__ Wk,
                              const float* __restrict__ Wv) {
  int i = blockIdx.x * blockDim.x + threadIdx.x;
  if (i >= C_ * CPAD) return;
  int o = i / CPAD, j = i - o * CPAD;
  float q = 0.f, kk = 0.f, v = 0.f;
  if (j < CP) {
    q = Wq[o * CP + j] * 0.35355339059327373f;  // fold 1/sqrt(D), D=8
    kk = Wk[o * CP + j];
    v = Wv[o * CP + j];
  }
  wpad[i] = q;
  wpad[C_ * CPAD + i] = kk;
  wpad[2 * C_ * CPAD + i] = v;
}

// XOR lane swizzle within 32-lane half (BitMode: and=0x1F, or=0, xor=mask)
#define SWZ(v, imm) __int_as_float(__builtin_amdgcn_ds_swizzle(__float_as_int(v), (imm)))
#define XOR1 0x041F
#define XOR2 0x081F
#define XOR4 0x101F
#define XOR8 0x201F

__launch_bounds__(256, 3)
__global__ void pt_attn(const float* __restrict__ pcd,
                        const float* __restrict__ neighbors,
                        const float* __restrict__ xyz,
                        const int* __restrict__ idx_all,
                        float* __restrict__ out) {
  __shared__ __align__(16) float x_lds[NP * CPAD];    // pcd_cat tile
  __shared__ float q_lds[NP * QSTRIDE];               // q tile
  __shared__ __align__(16) float e_lds[NP * ESTRIDE]; // e[h][j] = Wk_h^T q_h

  const int tid = threadIdx.x;
  const int p = tid >> 4;   // point within tile
  const int k = tid & 15;   // neighbor index
  const int blk = blockIdx.x;
  const int b = blk >> 10;             // N/NP = 1024 tiles per batch
  const int n0 = (blk & 1023) << 4;
  const int n = n0 + p;

  // ---- neighbor features (B,C,N,K) -> registers; perfectly coalesced:
  //      for each channel c the 256 threads read 256 contiguous floats ----
  float nb[CPAD];
  {
    const float* gp = neighbors + (size_t)b * (C_ * N_ * K_) + n0 * K_ + tid;
#pragma unroll
    for (int c = 0; c < C_; ++c)
      nb[c] = gp[(size_t)c * (N_ * K_)];
  }
  {
    const int idx = idx_all[(b * N_ + n) * K_ + k];
    const float* gx = xyz + (size_t)b * (3 * N_) + idx;
    nb[64] = gx[0];
    nb[65] = gx[N_];
    nb[66] = gx[2 * N_];
    nb[67] = 0.f;  // pad (weights pad col is 0 too)
  }

  // ---- stage x67 = concat(pcd, xyz) for the 16 points ----
  {
    const int pp = tid & 15;
    const int c0 = tid >> 4;  // 0..15
#pragma unroll
    for (int it = 0; it < 4; ++it) {
      int c = c0 + it * 16;
      x_lds[pp * CPAD + c] = pcd[((size_t)b * C_ + c) * N_ + n0 + pp];
    }
    if (tid < 48)
      x_lds[pp * CPAD + 64 + c0] = xyz[((size_t)b * 3 + c0) * N_ + n0 + pp];
    if (tid < 16)
      x_lds[pp * CPAD + 67] = 0.f;
  }
  __syncthreads();

  // ---- phase 1: q[o] for o = 4k..4k+3 of point p (Wq pre-scaled) ----
  {
    const float4* xr = (const float4*)(x_lds + p * CPAD);
    const float4* wq = (const float4*)(wpad) + 4 * k * 17;  // row stride 17 f4
    float a0 = 0.f, a1 = 0.f, a2 = 0.f, a3 = 0.f;
#pragma unroll
    for (int j4 = 0; j4 < 17; ++j4) {
      float4 xv = xr[j4];
      float4 w0 = wq[j4];
      float4 w1 = wq[17 + j4];
      float4 w2 = wq[34 + j4];
      float4 w3 = wq[51 + j4];
      a0 += w0.x * xv.x + w0.y * xv.y + w0.z * xv.z + w0.w * xv.w;
      a1 += w1.x * xv.x + w1.y * xv.y + w1.z * xv.z + w1.w * xv.w;
      a2 += w2.x * xv.x + w2.y * xv.y + w2.z * xv.z + w2.w * xv.w;
      a3 += w3.x * xv.x + w3.y * xv.y + w3.z * xv.z + w3.w * xv.w;
    }
    q_lds[p * QSTRIDE + 4 * k + 0] = a0;
    q_lds[p * QSTRIDE + 4 * k + 1] = a1;
    q_lds[p * QSTRIDE + 4 * k + 2] = a2;
    q_lds[p * QSTRIDE + 4 * k + 3] = a3;
  }
  __syncthreads();

  // ---- phase 2: e[h][j] = sum_d q[h*8+d] * Wk[h*8+d][j]  (h=k&7, j-half by k>>3;
  //      j4==8 is computed identically by both halves -> benign duplicate write) ----
  {
    const int h = k & 7;
    const int jh = k >> 3;
    float qa[8];
#pragma unroll
    for (int d = 0; d < 8; ++d)
      qa[d] = q_lds[p * QSTRIDE + h * 8 + d];
    const float4* wk = (const float4*)(wpad + C_ * CPAD) + h * 8 * 17;
    float4* er = (float4*)(e_lds + p * ESTRIDE + h * CPAD);
#pragma unroll
    for (int u = 0; u < 9; ++u) {
      int j4 = jh * 8 + u;
      float4 a = make_float4(0.f, 0.f, 0.f, 0.f);
#pragma unroll
      for (int d = 0; d < 8; ++d) {
        float4 w = wk[d * 17 + j4];
        a.x += qa[d] * w.x;
        a.y += qa[d] * w.y;
        a.z += qa[d] * w.z;
        a.w += qa[d] * w.w;
      }
      er[j4] = a;
    }
  }
  __syncthreads();

  // ---- phase 3: energies en[h] = e[h]·nb_k (scale already folded), softmax over k ----
  float en[8];
#pragma unroll
  for (int h = 0; h < 8; ++h) en[h] = 0.f;
  {
    const float4* ep = (const float4*)(e_lds + p * ESTRIDE);
#pragma unroll
    for (int j4 = 0; j4 < 17; ++j4) {
#pragma unroll
      for (int h = 0; h < 8; ++h) {
        float4 e4 = ep[h * 17 + j4];
        en[h] += e4.x * nb[4 * j4 + 0] + e4.y * nb[4 * j4 + 1] +
                 e4.z * nb[4 * j4 + 2] + e4.w * nb[4 * j4 + 3];
      }
    }
  }
  float at[8];
#pragma unroll
  for (int h = 0; h < 8; ++h) {
    float m = en[h];
    m = fmaxf(m, SWZ(m, XOR1));
    m = fmaxf(m, SWZ(m, XOR2));
    m = fmaxf(m, SWZ(m, XOR4));
    m = fmaxf(m, SWZ(m, XOR8));
    float e = __expf(en[h] - m);
    float s = e;
    s += SWZ(s, XOR1);
    s += SWZ(s, XOR2);
    s += SWZ(s, XOR4);
    s += SWZ(s, XOR8);
    at[h] = e * __builtin_amdgcn_rcpf(s);
  }

  // ---- permuted attn: ap[i] = at[i ^ g], g = k>>1, so the reduce-scatter below
  //      uses uniform register indices (no divergent array indexing) ----
  float ap[8];
  {
    const bool g2 = (k & 8) != 0;
    const bool g1 = (k & 4) != 0;
    const bool g0 = (k & 2) != 0;
    float t0[8], t1[8];
#pragma unroll
    for (int i = 0; i < 8; ++i) t0[i] = g2 ? at[i ^ 4] : at[i];
#pragma unroll
    for (int i = 0; i < 8; ++i) t1[i] = g1 ? t0[i ^ 2] : t0[i];
#pragma unroll
    for (int i = 0; i < 8; ++i) ap[i] = g0 ? t1[i ^ 1] : t1[i];
  }

  // ---- phase 4: agg_h[j] = sum_k attn[h,k]*nb_k[j] via 8-swizzle reduce-scatter;
  //      lane k ends with h = k>>1 and applies Wv rows o = 4k..4k+3 (h(o) = k>>1) ----
  float xo0 = 0.f, xo1 = 0.f, xo2 = 0.f, xo3 = 0.f;
  const float4* wv = (const float4*)(wpad + 2 * C_ * CPAD) + 4 * k * 17;
#pragma unroll
  for (int j4 = 0; j4 < 17; ++j4) {
    float agg0, agg1, agg2, agg3;
#pragma unroll
    for (int u = 0; u < 4; ++u) {
      float nbj = nb[4 * j4 + u];
      float s0 = ap[0] * nbj, s1 = ap[1] * nbj, s2 = ap[2] * nbj, s3 = ap[3] * nbj;
      float s4 = ap[4] * nbj, s5 = ap[5] * nbj, s6 = ap[6] * nbj, s7 = ap[7] * nbj;
      s0 += SWZ(s4, XOR8);
      s1 += SWZ(s5, XOR8);
      s2 += SWZ(s6, XOR8);
      s3 += SWZ(s7, XOR8);
      s0 += SWZ(s2, XOR4);
      s1 += SWZ(s3, XOR4);
      s0 += SWZ(s1, XOR2);
      s0 += SWZ(s0, XOR1);
      if (u == 0) agg0 = s0;
      else if (u == 1) agg1 = s0;
      else if (u == 2) agg2 = s0;
      else agg3 = s0;
    }
    float4 w0 = wv[j4];
    float4 w1 = wv[17 + j4];
    float4 w2 = wv[34 + j4];
    float4 w3 = wv[51 + j4];
    xo0 += w0.x * agg0 + w0.y * agg1 + w0.z * agg2 + w0.w * agg3;
    xo1 += w1.x * agg0 + w1.y * agg1 + w1.z * agg2 + w1.w * agg3;
    xo2 += w2.x * agg0 + w2.y * agg1 + w2.z * agg2 + w2.w * agg3;
    xo3 += w3.x * agg0 + w3.y * agg1 + w3.z * agg2 + w3.w * agg3;
  }

  // out[b][o][n], o = 4k+i
  float* op = out + ((size_t)b * C_ + 4 * k) * N_ + n0 + p;
  op[0] = xo0;
  op[(size_t)N_] = xo1;
  op[2 * (size_t)N_] = xo2;
  op[3 * (size_t)N_] = xo3;
}

extern "C" void kernel_launch(void* const* d_in, const int* in_sizes, int n_in,
                              void* d_out, int out_size, void* d_ws, size_t ws_size,
                              hipStream_t stream) {
  const float* pcd = (const float*)d_in[0];
  const float* neighbors = (const float*)d_in[1];
  const float* xyz = (const float*)d_in[2];
  const float* Wq = (const float*)d_in[3];
  const float* Wk = (const float*)d_in[4];
  const float* Wv = (const float*)d_in[5];
  const int* idx = (const int*)d_in[6];
  float* out = (float*)d_out;

  setup_weights<<<(C_ * CPAD + 255) / 256, 256, 0, stream>>>(Wq, Wk, Wv);
  pt_attn<<<B_ * (N_ / NP), 256, 0, stream>>>(pcd, neighbors, xyz, idx, out);
}